// Round 2
// baseline (397.626 us; speedup 1.0000x reference)
//
#include <hip/hip_runtime.h>
#include <math.h>

// Problem constants (from reference setup_inputs): N=1024, D=65536, T=64, K=100
#define TSPAN  64
#define CROWS  16        // N / TSPAN
#define DCOLS  65536
#define NPASS  9         // 7 soft-removes + (m1 + 8th soft-remove) + m2

__global__ __launch_bounds__(256) void find_median_kernel(
    const float* __restrict__ in, float* __restrict__ out)
{
    // Match numpy fp32 semantics: no fma contraction (np never fuses mul+sub).
    #pragma clang fp contract(off)

    const int tid = blockIdx.x * blockDim.x + threadIdx.x;   // tid = t*DCOLS + d
    const int t = tid >> 16;            // DCOLS = 2^16
    const int d = tid & (DCOLS - 1);

    float x[CROWS];
    const size_t base = (size_t)t * (CROWS * (size_t)DCOLS) + (size_t)d;
    #pragma unroll
    for (int r = 0; r < CROWS; ++r)
        x[r] = in[base + (size_t)r * DCOLS] * 100.0f;   // x = input * k, bit-exact vs np

    float m1 = 0.0f, m2 = 0.0f;

    #pragma unroll
    for (int pass = 0; pass < NPASS; ++pass) {
        // column max (exact, order-independent)
        float m = fmaxf(fmaxf(fmaxf(x[0], x[1]), fmaxf(x[2], x[3])),
                        fmaxf(fmaxf(x[4], x[5]), fmaxf(x[6], x[7])));
        m = fmaxf(m, fmaxf(fmaxf(fmaxf(x[8],  x[9]),  fmaxf(x[10], x[11])),
                           fmaxf(fmaxf(x[12], x[13]), fmaxf(x[14], x[15]))));

        // e = exp(x - m), libm expf (~1 ulp, same class as np's)
        float e[CROWS];
        #pragma unroll
        for (int r = 0; r < CROWS; ++r)
            e[r] = expf(x[r] - m);

        // sequential sum (np strided-axis reduction order)
        float s = e[0];
        #pragma unroll
        for (int r = 1; r < CROWS; ++r)
            s = s + e[r];

        if (pass == 7) m1 = m + logf(s);             // logsumexp #1
        if (pass == 8) { m2 = m + logf(s); break; }  // logsumexp #2

        // soft remove: x <- x - softmax(x)*x, true IEEE division per element (as np)
        #pragma unroll
        for (int r = 0; r < CROWS; ++r) {
            const float p = e[r] / s;
            const float pr = p * x[r];
            x[r] = x[r] - pr;
        }
    }

    // median = (m1+m2)/2 ; return median / k.  (/2 is exact as *0.5f)
    out[tid] = ((m1 + m2) * 0.5f) / 100.0f;
}

extern "C" void kernel_launch(void* const* d_in, const int* in_sizes, int n_in,
                              void* d_out, int out_size, void* d_ws, size_t ws_size,
                              hipStream_t stream)
{
    const float* in = (const float*)d_in[0];
    float* out = (float*)d_out;

    const int total = TSPAN * DCOLS;          // 4,194,304 threads, one column each
    const int block = 256;
    const int grid = total / block;           // 16384

    find_median_kernel<<<grid, block, 0, stream>>>(in, out);
}

// Round 3
// 140.990 us; speedup vs baseline: 2.8202x; 2.8202x over previous
//
#include <hip/hip_runtime.h>
#include <math.h>

// Problem constants (from reference setup_inputs): N=1024, D=65536, T=64, K=100
#define TSPAN  64
#define CROWS  16        // N / TSPAN
#define DCOLS  65536
#define NPASS  9         // 7 soft-removes + (m1 + 8th soft-remove) + m2

__global__ __launch_bounds__(256) void find_median_kernel(
    const float* __restrict__ in, float* __restrict__ out)
{
    // Keep np's unfused mul/sub semantics for the state update.
    #pragma clang fp contract(off)

    const int tid = blockIdx.x * blockDim.x + threadIdx.x;   // tid = t*DCOLS + d
    const int t = tid >> 16;            // DCOLS = 2^16
    const int d = tid & (DCOLS - 1);

    const float LOG2E = 1.4426950408889634f;

    float x[CROWS];
    const size_t base = (size_t)t * (CROWS * (size_t)DCOLS) + (size_t)d;
    #pragma unroll
    for (int r = 0; r < CROWS; ++r)
        x[r] = in[base + (size_t)r * DCOLS] * 100.0f;   // x = input * k (bit-exact vs np)

    float m1 = 0.0f, m2 = 0.0f;

    #pragma unroll
    for (int pass = 0; pass < NPASS; ++pass) {
        // column max (exact)
        float m = fmaxf(fmaxf(fmaxf(x[0], x[1]), fmaxf(x[2], x[3])),
                        fmaxf(fmaxf(x[4], x[5]), fmaxf(x[6], x[7])));
        m = fmaxf(m, fmaxf(fmaxf(fmaxf(x[8],  x[9]),  fmaxf(x[10], x[11])),
                           fmaxf(fmaxf(x[12], x[13]), fmaxf(x[14], x[15]))));

        // e = exp(x-m) via hardware exp2: e = 2^((x-m)*log2e).
        // Tail terms (large |x-m|) pick up relative error ~ ln2*|t|*eps but have
        // negligible softmax weight, so the perturbation vs libm expf is ~ulp-level
        // where it matters.
        float e[CROWS];
        #pragma unroll
        for (int r = 0; r < CROWS; ++r)
            e[r] = __builtin_amdgcn_exp2f((x[r] - m) * LOG2E);

        // sequential sum (np reduction order)
        float s = e[0];
        #pragma unroll
        for (int r = 1; r < CROWS; ++r)
            s = s + e[r];

        if (pass == 7) m1 = m + logf(s);             // logsumexp #1 (2 calls total: keep libm)
        if (pass == 8) { m2 = m + logf(s); break; }  // logsumexp #2

        // 1/s via rcp + one Newton step: ~1 ulp, unbiased (raw rcp's 2.4e-7 bias
        // would compound coherently across the 8 passes).
        float inv = __builtin_amdgcn_rcpf(s);
        inv = inv * fmaf(-s, inv, 2.0f);

        // soft remove: x <- x - (e*inv)*x  (matches np's x - softmax*x up to ~1 ulp)
        #pragma unroll
        for (int r = 0; r < CROWS; ++r) {
            const float p  = e[r] * inv;
            const float pr = p * x[r];
            x[r] = x[r] - pr;
        }
    }

    // median = (m1+m2)/2 ; return median / k.
    out[tid] = ((m1 + m2) * 0.5f) / 100.0f;
}

extern "C" void kernel_launch(void* const* d_in, const int* in_sizes, int n_in,
                              void* d_out, int out_size, void* d_ws, size_t ws_size,
                              hipStream_t stream)
{
    const float* in = (const float*)d_in[0];
    float* out = (float*)d_out;

    const int total = TSPAN * DCOLS;          // 4,194,304 threads, one column each
    const int block = 256;
    const int grid = total / block;           // 16384

    find_median_kernel<<<grid, block, 0, stream>>>(in, out);
}

// Round 4
// 125.883 us; speedup vs baseline: 3.1587x; 1.1200x over previous
//
#include <hip/hip_runtime.h>
#include <math.h>

// Problem constants (from reference setup_inputs): N=1024, D=65536, T=64, K=100
#define TSPAN  64
#define CROWS  16        // N / TSPAN
#define DCOLS  65536
#define NPASS  9         // 7 soft-removes + (m1 + 8th soft-remove) + m2

// __launch_bounds__(256, 8): 8 waves/EU min -> VGPR cap 64. Round-3 binary was
// squeezed to 20 VGPRs, forcing rematerialization of all 16 exp2's in the
// update loop (~30 trans + 32 VALU extra per pass). We need ~44 VGPRs to keep
// e[16] live; 64-cap still allows 8 waves/SIMD = full occupancy.
__global__ __launch_bounds__(256, 8) void find_median_kernel(
    const float* __restrict__ in, float* __restrict__ out)
{
    // Keep np's unfused mul/sub semantics for the state update.
    #pragma clang fp contract(off)

    const int tid = blockIdx.x * blockDim.x + threadIdx.x;   // tid = t*DCOLS + d
    const int t = tid >> 16;            // DCOLS = 2^16
    const int d = tid & (DCOLS - 1);

    const float LOG2E = 1.4426950408889634f;

    float x[CROWS];
    const size_t base = (size_t)t * (CROWS * (size_t)DCOLS) + (size_t)d;
    #pragma unroll
    for (int r = 0; r < CROWS; ++r)
        x[r] = in[base + (size_t)r * DCOLS] * 100.0f;   // x = input * k (bit-exact vs np)

    float m1 = 0.0f, m2 = 0.0f;

    #pragma unroll
    for (int pass = 0; pass < NPASS; ++pass) {
        // column max via v_max3_f32 triples (exact; 8 ops instead of 15)
        const float a0 = fmaxf(fmaxf(x[0],  x[1]),  x[2]);
        const float a1 = fmaxf(fmaxf(x[3],  x[4]),  x[5]);
        const float a2 = fmaxf(fmaxf(x[6],  x[7]),  x[8]);
        const float a3 = fmaxf(fmaxf(x[9],  x[10]), x[11]);
        const float a4 = fmaxf(fmaxf(x[12], x[13]), x[14]);
        const float b0 = fmaxf(fmaxf(a0, a1), a2);
        const float b1 = fmaxf(fmaxf(a3, a4), x[15]);
        const float m  = fmaxf(b0, b1);

        // e = exp(x-m) = 2^(x*log2e - m*log2e), arg via single fma.
        // Rounding of mL is COMMON to all rows -> scales every e[r] by the same
        // 2^delta, which cancels exactly in softmax (p=e/s) and shifts LSE by
        // only delta*ln2 ~ 5e-6. Differential error stays ulp-level.
        const float mL = m * LOG2E;
        float e[CROWS];
        #pragma unroll
        for (int r = 0; r < CROWS; ++r)
            e[r] = __builtin_amdgcn_exp2f(fmaf(x[r], LOG2E, -mL));

        // sequential sum (np reduction order)
        float s = e[0];
        #pragma unroll
        for (int r = 1; r < CROWS; ++r)
            s = s + e[r];

        if (pass == 7) m1 = m + logf(s);             // logsumexp #1
        if (pass == 8) { m2 = m + logf(s); break; }  // logsumexp #2

        // 1/s via rcp + one Newton step: ~1 ulp, unbiased.
        float inv = __builtin_amdgcn_rcpf(s);
        inv = inv * fmaf(-s, inv, 2.0f);

        // soft remove: x <- x - (e*inv)*x  -- identical op sequence to the
        // passing round-3 kernel (no new rounding behavior in the state path).
        #pragma unroll
        for (int r = 0; r < CROWS; ++r) {
            const float p  = e[r] * inv;
            const float pr = p * x[r];
            x[r] = x[r] - pr;
        }
    }

    // median = (m1+m2)/2 ; return median / k.
    out[tid] = ((m1 + m2) * 0.5f) / 100.0f;
}

extern "C" void kernel_launch(void* const* d_in, const int* in_sizes, int n_in,
                              void* d_out, int out_size, void* d_ws, size_t ws_size,
                              hipStream_t stream)
{
    const float* in = (const float*)d_in[0];
    float* out = (float*)d_out;

    const int total = TSPAN * DCOLS;          // 4,194,304 threads, one column each
    const int block = 256;
    const int grid = total / block;           // 16384

    find_median_kernel<<<grid, block, 0, stream>>>(in, out);
}

// Round 5
// 123.470 us; speedup vs baseline: 3.2204x; 1.0195x over previous
//
#include <hip/hip_runtime.h>
#include <math.h>

// Problem constants (from reference setup_inputs): N=1024, D=65536, T=64, K=100
#define TSPAN  64
#define CROWS  16        // N / TSPAN
#define DCOLS  65536
#define NPASS  9         // 7 soft-removes + (m1 + 8th soft-remove) + m2

// Pin a value into a VGPR: empty asm with read-write constraint makes the
// value opaque -> register allocator CANNOT rematerialize it downstream.
// Round-3 binary had VGPR_Count=20: e[16] was being recomputed (16 fma +
// 16 v_exp_f32 extra per update pass). Zero-instruction fix.
#define KEEP(v) asm("" : "+v"(v))

__global__ __launch_bounds__(256, 8) void find_median_kernel(
    const float* __restrict__ in, float* __restrict__ out)
{
    // Keep np's unfused mul/sub semantics for the state update.
    #pragma clang fp contract(off)

    const int tid = blockIdx.x * blockDim.x + threadIdx.x;   // tid = t*DCOLS + d
    const int t = tid >> 16;            // DCOLS = 2^16
    const int d = tid & (DCOLS - 1);

    const float LOG2E = 1.4426950408889634f;
    const float LN2   = 0.6931471805599453f;

    float x[CROWS];
    const size_t base = (size_t)t * (CROWS * (size_t)DCOLS) + (size_t)d;
    #pragma unroll
    for (int r = 0; r < CROWS; ++r)
        x[r] = in[base + (size_t)r * DCOLS] * 100.0f;   // x = input * k (bit-exact vs np)

    float m1 = 0.0f, m2 = 0.0f;

    #pragma unroll
    for (int pass = 0; pass < NPASS; ++pass) {
        // column max via v_max3_f32 triples (exact; 8 ops)
        const float a0 = fmaxf(fmaxf(x[0],  x[1]),  x[2]);
        const float a1 = fmaxf(fmaxf(x[3],  x[4]),  x[5]);
        const float a2 = fmaxf(fmaxf(x[6],  x[7]),  x[8]);
        const float a3 = fmaxf(fmaxf(x[9],  x[10]), x[11]);
        const float a4 = fmaxf(fmaxf(x[12], x[13]), x[14]);
        const float b0 = fmaxf(fmaxf(a0, a1), a2);
        const float b1 = fmaxf(fmaxf(a3, a4), x[15]);
        const float m  = fmaxf(b0, b1);

        // e = exp(x-m) = 2^(x*log2e - m*log2e); mL rounding is common-mode
        // across the column -> cancels in softmax, ~5e-6 shift in LSE.
        const float mL = m * LOG2E;
        float e[CROWS];
        #pragma unroll
        for (int r = 0; r < CROWS; ++r) {
            e[r] = __builtin_amdgcn_exp2f(fmaf(x[r], LOG2E, -mL));
            KEEP(e[r]);   // force e[] live across the sum: no remat in update loop
        }

        // sequential sum (np reduction order)
        float s = e[0];
        #pragma unroll
        for (int r = 1; r < CROWS; ++r)
            s = s + e[r];

        // logsumexp via hardware log2: m + log2(s)*ln2 (output path only,
        // not amplified by the iteration; ~1e-6 vs libm logf)
        if (pass == 7) m1 = fmaf(__builtin_amdgcn_logf(s), LN2, m);
        if (pass == 8) { m2 = fmaf(__builtin_amdgcn_logf(s), LN2, m); break; }

        // 1/s via rcp + one Newton step: ~1 ulp, unbiased.
        float inv = __builtin_amdgcn_rcpf(s);
        inv = inv * fmaf(-s, inv, 2.0f);

        // soft remove: x <- x - (e*inv)*x  -- same op sequence as the passing
        // round-3/4 kernels (absmax 0.0059 vs threshold 0.0127).
        #pragma unroll
        for (int r = 0; r < CROWS; ++r) {
            const float p  = e[r] * inv;
            const float pr = p * x[r];
            x[r] = x[r] - pr;
        }
    }

    // median = (m1+m2)/2 ; return median / k.
    out[tid] = ((m1 + m2) * 0.5f) / 100.0f;
}

extern "C" void kernel_launch(void* const* d_in, const int* in_sizes, int n_in,
                              void* d_out, int out_size, void* d_ws, size_t ws_size,
                              hipStream_t stream)
{
    const float* in = (const float*)d_in[0];
    float* out = (float*)d_out;

    const int total = TSPAN * DCOLS;          // 4,194,304 threads, one column each
    const int block = 256;
    const int grid = total / block;           // 16384

    find_median_kernel<<<grid, block, 0, stream>>>(in, out);
}

// Round 6
// 107.497 us; speedup vs baseline: 3.6989x; 1.1486x over previous
//
#include <hip/hip_runtime.h>
#include <math.h>

// Problem constants (from reference setup_inputs): N=1024, D=65536, T=64, K=100
#define TSPAN  64
#define CROWS  16        // N / TSPAN
#define DCOLS  65536
#define NPASS  9         // 7 soft-removes + (m1 + 8th soft-remove) + m2

// Pin a value into a VGPR (opaque to the allocator -> cannot rematerialize).
#define KEEP(v) asm("" : "+v"(v))

__global__ __launch_bounds__(256, 8) void find_median_kernel(
    const float* __restrict__ in, float* __restrict__ out)
{
    // np never fuses its mul/sub; keep contraction off and fuse ONLY where we
    // explicitly choose fmaf.
    #pragma clang fp contract(off)

    const int tid = blockIdx.x * blockDim.x + threadIdx.x;   // tid = t*DCOLS + d
    const int t = tid >> 16;            // DCOLS = 2^16
    const int d = tid & (DCOLS - 1);

    const float LOG2E = 1.4426950408889634f;
    const float LN2   = 0.6931471805599453f;

    float x[CROWS];
    const size_t base = (size_t)t * (CROWS * (size_t)DCOLS) + (size_t)d;
    #pragma unroll
    for (int r = 0; r < CROWS; ++r)
        x[r] = in[base + (size_t)r * DCOLS] * 100.0f;   // x = input * k (bit-exact vs np)

    float m1 = 0.0f, m2 = 0.0f;

    #pragma unroll
    for (int pass = 0; pass < NPASS; ++pass) {
        // column max via v_max3_f32 triples (exact; 8 ops)
        const float a0 = fmaxf(fmaxf(x[0],  x[1]),  x[2]);
        const float a1 = fmaxf(fmaxf(x[3],  x[4]),  x[5]);
        const float a2 = fmaxf(fmaxf(x[6],  x[7]),  x[8]);
        const float a3 = fmaxf(fmaxf(x[9],  x[10]), x[11]);
        const float a4 = fmaxf(fmaxf(x[12], x[13]), x[14]);
        const float b0 = fmaxf(fmaxf(a0, a1), a2);
        const float b1 = fmaxf(fmaxf(a3, a4), x[15]);
        const float m  = fmaxf(b0, b1);

        // e = exp(x-m) = 2^(x*log2e - m*log2e); mL rounding is common-mode
        // across the column -> cancels in softmax; ~5e-6 shift in LSE only.
        const float mL = m * LOG2E;
        float e[CROWS];
        #pragma unroll
        for (int r = 0; r < CROWS; ++r) {
            e[r] = __builtin_amdgcn_exp2f(fmaf(x[r], LOG2E, -mL));
            KEEP(e[r]);   // keep e[] live across the sum (no remat in update)
        }

        // sequential sum (np reduction order)
        float s = e[0];
        #pragma unroll
        for (int r = 1; r < CROWS; ++r)
            s = s + e[r];

        // logsumexp via hardware log2 (output path only, ~1e-6 vs libm)
        if (pass == 7) m1 = fmaf(__builtin_amdgcn_logf(s), LN2, m);
        if (pass == 8) { m2 = fmaf(__builtin_amdgcn_logf(s), LN2, m); break; }

        // 1/s via rcp + one Newton step: ~1 ulp, unbiased.
        float inv = __builtin_amdgcn_rcpf(s);
        inv = inv * fmaf(-s, inv, 2.0f);

        // soft remove, fused: q = e/s (~1 ulp), x <- fma(-q, x, x).
        // q*x is exact inside the fma, single rounding on the subtract —
        // per-pass perturbation vs np stays ~1 ulp random (same class as the
        // 3-op version that passed at absmax 0.0059).
        #pragma unroll
        for (int r = 0; r < CROWS; ++r) {
            const float q = e[r] * inv;
            x[r] = fmaf(-q, x[r], x[r]);
        }
    }

    // median = (m1+m2)/2 ; return median / k.
    out[tid] = ((m1 + m2) * 0.5f) / 100.0f;
}

extern "C" void kernel_launch(void* const* d_in, const int* in_sizes, int n_in,
                              void* d_out, int out_size, void* d_ws, size_t ws_size,
                              hipStream_t stream)
{
    const float* in = (const float*)d_in[0];
    float* out = (float*)d_out;

    const int total = TSPAN * DCOLS;          // 4,194,304 threads, one column each
    const int block = 256;
    const int grid = total / block;           // 16384

    find_median_kernel<<<grid, block, 0, stream>>>(in, out);
}